// Round 2
// baseline (256.747 us; speedup 1.0000x reference)
//
#include <hip/hip_runtime.h>

// out = kipf - lbda[:,None] * input
// N_NODES=100000, N_FEATURES=256, f32. Pure elementwise streaming, 307 MB logical.
//
// R2 = R1 with the compile fix: __builtin_nontemporal_store needs a clang native
// vector type, not HIP's struct float4. Use ext_vector_type(4) float throughout.
//
// R1 rationale (unchanged):
//  - nontemporal stores: output (102 MB, never re-read) no longer write-allocates,
//    so the 205 MB of inputs stay resident in the 256 MB Infinity Cache
//    (baseline FETCH_SIZE ~= one full input re-fetch = eviction evidence).
//  - grid-stride with compile-time trip count ITERS=10, grid capped at 2500 blocks:
//    10 independent float4 load-pairs in flight per thread (ILP for latency hiding).

typedef float floatx4 __attribute__((ext_vector_type(4)));

constexpr int BLOCK = 256;
constexpr int ITERS = 10;   // float4 per thread; 6.4e6 / (2500*256) = 10 exactly

__global__ __launch_bounds__(BLOCK) void damping_kernel(
    const floatx4* __restrict__ input4,
    const floatx4* __restrict__ kipf4,
    const float* __restrict__ lbda,
    floatx4* __restrict__ out4,
    int n4)  // total float4 elements = N_NODES * 64
{
    const int stride = gridDim.x * BLOCK;
    int i = blockIdx.x * BLOCK + threadIdx.x;
#pragma unroll
    for (int it = 0; it < ITERS; ++it, i += stride) {
        if (i < n4) {
            int row = i >> 6;               // 64 float4 per 256-float row
            float l = lbda[row];            // wave-uniform broadcast, cache-served
            floatx4 a = input4[i];
            floatx4 k = kipf4[i];
            floatx4 o = k - l * a;          // native vector math, 4x v_fma/v_sub
            __builtin_nontemporal_store(o, &out4[i]);   // nt store, bypass cache
        }
    }
}

extern "C" void kernel_launch(void* const* d_in, const int* in_sizes, int n_in,
                              void* d_out, int out_size, void* d_ws, size_t ws_size,
                              hipStream_t stream) {
    const floatx4* input4 = (const floatx4*)d_in[0];   // input_term (100000,256) f32
    const floatx4* kipf4  = (const floatx4*)d_in[1];   // kipf_term  (100000,256) f32
    const float*   lbda   = (const float*)d_in[2];     // lbda (100000,) f32
    // d_in[3] = spar (scalar int, always 1 in this path) -- unused
    floatx4* out4 = (floatx4*)d_out;

    int n4 = out_size / 4;                           // 6,400,000 float4
    int per_block = BLOCK * ITERS;                   // 2560 float4 per block
    int grid = (n4 + per_block - 1) / per_block;     // 2500 blocks (~9.8/CU)
    damping_kernel<<<grid, BLOCK, 0, stream>>>(input4, kipf4, lbda, out4, n4);
}

// Round 3
// 248.304 us; speedup vs baseline: 1.0340x; 1.0340x over previous
//
#include <hip/hip_runtime.h>

// out = kipf - lbda[:,None] * input
// N_NODES=100000, N_FEATURES=256, f32. Streaming, 307 MB logical / ~204 MB HBM
// (harness re-poison cycles 307 MB through the 256 MB L3 between dispatches, so
//  ~one input's worth always misses — FETCH ~= 101.5 MB is structural, R2 lesson).
//
// R3: isolate the R2 regression (nt store, -12%) and test read-MLP as the limiter:
//  - NO nontemporal store (back to cached stores).
//  - grid-stride, ITERS=4 per thread, grid = 6250 blocks (exact: 6250*256*4 = 6.4e6).
//  - explicit load-batching: all 8 dwordx4 loads issued before any compute/store,
//    so each wave holds 8 KB of reads in flight instead of 2 KB.
//  - ITERS=4 keeps data regs at 32 + addr overhead < 64 VGPR -> 32 waves/CU.

typedef float floatx4 __attribute__((ext_vector_type(4)));

constexpr int BLOCK = 256;
constexpr int ITERS = 4;

__global__ __launch_bounds__(BLOCK) void damping_kernel(
    const floatx4* __restrict__ input4,
    const floatx4* __restrict__ kipf4,
    const float* __restrict__ lbda,
    floatx4* __restrict__ out4,
    int n4)  // total float4 elements = N_NODES * 64 = 6,400,000
{
    const int stride = gridDim.x * BLOCK;
    const int i0 = blockIdx.x * BLOCK + threadIdx.x;

    if (i0 + (ITERS - 1) * stride < n4) {
        // fast path: all ITERS indices in bounds (exact for this problem size)
        floatx4 a[ITERS], k[ITERS];
        float l[ITERS];
        int i = i0;
#pragma unroll
        for (int it = 0; it < ITERS; ++it, i += stride) {
            a[it] = input4[i];              // 8 independent global loads issued
            k[it] = kipf4[i];               // back-to-back: 8 KB/wave in flight
            l[it] = lbda[i >> 6];
        }
        i = i0;
#pragma unroll
        for (int it = 0; it < ITERS; ++it, i += stride) {
            out4[i] = k[it] - l[it] * a[it];
        }
    } else {
        // tail path (not taken at this problem size)
        for (int i = i0; i < n4; i += stride) {
            float l = lbda[i >> 6];
            floatx4 a = input4[i];
            floatx4 k = kipf4[i];
            out4[i] = k - l * a;
        }
    }
}

extern "C" void kernel_launch(void* const* d_in, const int* in_sizes, int n_in,
                              void* d_out, int out_size, void* d_ws, size_t ws_size,
                              hipStream_t stream) {
    const floatx4* input4 = (const floatx4*)d_in[0];   // input_term (100000,256) f32
    const floatx4* kipf4  = (const floatx4*)d_in[1];   // kipf_term  (100000,256) f32
    const float*   lbda   = (const float*)d_in[2];     // lbda (100000,) f32
    // d_in[3] = spar (scalar int, always 1 in this path) -- unused
    floatx4* out4 = (floatx4*)d_out;

    int n4 = out_size / 4;                             // 6,400,000 float4
    int per_block = BLOCK * ITERS;                     // 1024 float4 per block
    int grid = (n4 + per_block - 1) / per_block;       // 6250 blocks (~24.4/CU)
    damping_kernel<<<grid, BLOCK, 0, stream>>>(input4, kipf4, lbda, out4, n4);
}

// Round 4
// 246.975 us; speedup vs baseline: 1.0396x; 1.0054x over previous
//
#include <hip/hip_runtime.h>

// out = kipf - lbda[:,None] * input
// N_NODES=100000, N_FEATURES=256, f32. Streaming, 307 MB logical / ~206 MB HBM
// (FETCH ~= one matrix is structural: harness poison cycles the 256 MB L3).
//
// R4: R3's MLP test was VOID — VGPR_Count=24 proved the compiler re-interleaved
// the "batched" loads (restrict makes that legal). This version forces the batch:
//  - named scalar regs (no arrays -> no scratch risk, no re-rolling)
//  - asm memory clobber between load block and store block: loads cannot sink
//    below it, stores cannot hoist above it -> 8 dwordx4 (8 KB/wave) truly in
//    flight before the first s_waitcnt.
//  - ITERS=4, grid=6250 exact; ~48 VGPR stays <=64 -> full 8 waves/SIMD.
// Success criterion: VGPR_Count >= 40. Then: dur drop => latency-bound confirmed;
// flat => latency ruled out, next lever is store cache policy.

typedef float floatx4 __attribute__((ext_vector_type(4)));

constexpr int BLOCK = 256;
constexpr int ITERS = 4;

__global__ __launch_bounds__(BLOCK) void damping_kernel(
    const floatx4* __restrict__ input4,
    const floatx4* __restrict__ kipf4,
    const float* __restrict__ lbda,
    floatx4* __restrict__ out4,
    int n4)  // total float4 elements = N_NODES * 64 = 6,400,000
{
    const int stride = gridDim.x * BLOCK;
    const int i0 = blockIdx.x * BLOCK + threadIdx.x;
    const int i1 = i0 + stride;
    const int i2 = i1 + stride;
    const int i3 = i2 + stride;

    if (i3 < n4) {
        // fast path (exact at this problem size: 6250*256*4 == n4)
        floatx4 a0 = input4[i0], k0 = kipf4[i0];
        floatx4 a1 = input4[i1], k1 = kipf4[i1];
        floatx4 a2 = input4[i2], k2 = kipf4[i2];
        floatx4 a3 = input4[i3], k3 = kipf4[i3];
        float l0 = lbda[i0 >> 6];
        float l1 = lbda[i1 >> 6];
        float l2 = lbda[i2 >> 6];
        float l3 = lbda[i3 >> 6];
        // scheduling fence: no store may hoist above, no load may sink below
        asm volatile("" ::: "memory");
        out4[i0] = k0 - l0 * a0;
        out4[i1] = k1 - l1 * a1;
        out4[i2] = k2 - l2 * a2;
        out4[i3] = k3 - l3 * a3;
    } else {
        // tail (not taken at this size)
        for (int i = i0; i < n4; i += stride) {
            float l = lbda[i >> 6];
            floatx4 a = input4[i];
            floatx4 k = kipf4[i];
            out4[i] = k - l * a;
        }
    }
}

extern "C" void kernel_launch(void* const* d_in, const int* in_sizes, int n_in,
                              void* d_out, int out_size, void* d_ws, size_t ws_size,
                              hipStream_t stream) {
    const floatx4* input4 = (const floatx4*)d_in[0];   // input_term (100000,256) f32
    const floatx4* kipf4  = (const floatx4*)d_in[1];   // kipf_term  (100000,256) f32
    const float*   lbda   = (const float*)d_in[2];     // lbda (100000,) f32
    // d_in[3] = spar (scalar int, always 1 in this path) -- unused
    floatx4* out4 = (floatx4*)d_out;

    int n4 = out_size / 4;                             // 6,400,000 float4
    int per_block = BLOCK * ITERS;                     // 1024 float4 per block
    int grid = (n4 + per_block - 1) / per_block;       // 6250 blocks
    damping_kernel<<<grid, BLOCK, 0, stream>>>(input4, kipf4, lbda, out4, n4);
}

// Round 5
// 233.579 us; speedup vs baseline: 1.0992x; 1.0573x over previous
//
#include <hip/hip_runtime.h>

// out = kipf - lbda[:,None] * input
// N_NODES=100000, N_FEATURES=256, f32. Streaming, 307 MB logical.
//
// R5 theory: in-window HBM traffic = 101.5 MB read-misses + 100 MB of *victim
// write-backs* (dirty poison/output lines evicted by my read allocations into a
// full 256 MB L3). Read-ILP is ruled out (R3/R4 null); nt STORES hurt (R2).
// This round: NON-TEMPORAL LOADS (no-allocate) on the two 102 MB input streams:
//  - read misses stop evicting dirty output lines -> their write-back defers out
//    of my dispatch window (poison re-dirties the same lines anyway)
//  - the L3-resident input half stops being thrashed mid-kernel
// Structure: R0's (fastest measured: 88.6 us) one-thread-per-float4, cached stores.
// Success signature: WRITE_SIZE << 100 MB. Kernel dur predicted 55-75 us.

typedef float floatx4 __attribute__((ext_vector_type(4)));

__global__ __launch_bounds__(256) void damping_kernel(
    const floatx4* __restrict__ input4,
    const floatx4* __restrict__ kipf4,
    const float* __restrict__ lbda,
    floatx4* __restrict__ out4,
    int n4)  // total float4 elements = N_NODES * 64 = 6,400,000
{
    int i = blockIdx.x * blockDim.x + threadIdx.x;
    if (i >= n4) return;
    int row = i >> 6;                    // 64 float4 per 256-float row
    float l = lbda[row];                 // wave-uniform, cached (broadcast)
    floatx4 a = __builtin_nontemporal_load(&input4[i]);  // no-allocate read
    floatx4 k = __builtin_nontemporal_load(&kipf4[i]);   // no-allocate read
    floatx4 o = k - l * a;
    out4[i] = o;                         // normal cached store (nt store = -12%, R2)
}

extern "C" void kernel_launch(void* const* d_in, const int* in_sizes, int n_in,
                              void* d_out, int out_size, void* d_ws, size_t ws_size,
                              hipStream_t stream) {
    const floatx4* input4 = (const floatx4*)d_in[0];   // input_term (100000,256) f32
    const floatx4* kipf4  = (const floatx4*)d_in[1];   // kipf_term  (100000,256) f32
    const float*   lbda   = (const float*)d_in[2];     // lbda (100000,) f32
    // d_in[3] = spar (scalar int, always 1 in this path) -- unused
    floatx4* out4 = (floatx4*)d_out;

    int n4 = out_size / 4;                           // 6,400,000 float4
    int block = 256;
    int grid = (n4 + block - 1) / block;             // 25000 blocks
    damping_kernel<<<grid, block, 0, stream>>>(input4, kipf4, lbda, out4, n4);
}